// Round 1
// baseline (2510.903 us; speedup 1.0000x reference)
//
#include <hip/hip_runtime.h>

// ---------------------------------------------------------------------------
// Wiener 3D patch filter, MI355X.
// Input:  I (4,3,512,512) f32, noise_std (4,3,512,512) f32
// Output: (4,3,512,512) f32
// One 128-thread block per (b, py, px) patch location (py,px in [1,67]).
// ---------------------------------------------------------------------------

constexpr float TWR[16] = {
  1.0f, 0.98078528040323044f, 0.92387953251128674f, 0.83146961230254524f,
  0.70710678118654752f, 0.55557023301960222f, 0.38268343236508977f, 0.19509032201612827f,
  0.0f, -0.19509032201612827f, -0.38268343236508977f, -0.55557023301960222f,
  -0.70710678118654752f, -0.83146961230254524f, -0.92387953251128674f, -0.98078528040323044f
};
// TWI[k] = -sin(2*pi*k/32)  (forward twiddle imag part)
constexpr float TWI[16] = {
  -0.0f, -0.19509032201612827f, -0.38268343236508977f, -0.55557023301960222f,
  -0.70710678118654752f, -0.83146961230254524f, -0.92387953251128674f, -0.98078528040323044f,
  -1.0f, -0.98078528040323044f, -0.92387953251128674f, -0.83146961230254524f,
  -0.70710678118654752f, -0.55557023301960222f, -0.38268343236508977f, -0.19509032201612827f
};
constexpr int REV5[32] = {0,16,8,24,4,20,12,28,2,18,10,26,6,22,14,30,
                          1,17,9,25,5,21,13,29,3,19,11,27,7,23,15,31};

constexpr float S3   = 0.86602540378443865f;  // sqrt(3)/2
constexpr float EPSF = 1e-15f;
constexpr float INV_WIN_DEN = -1.0f / 76.8f;  // -1/(0.3*16*16)

template<int SIGN, int S>
__device__ __forceinline__ void fft_stage(float* ar, float* ai) {
  constexpr int m  = 1 << S;
  constexpr int h  = m >> 1;
  constexpr int ts = 32 >> S;
  #pragma unroll
  for (int k = 0; k < 32; k += m) {
    #pragma unroll
    for (int j = 0; j < h; ++j) {
      const float wr = TWR[j * ts];
      const float wi = (SIGN < 0) ? TWI[j * ts] : -TWI[j * ts];
      const int u = k + j, v = u + h;
      float tr = wr * ar[v] - wi * ai[v];
      float ti = wr * ai[v] + wi * ar[v];
      ar[v] = ar[u] - tr;  ai[v] = ai[u] - ti;
      ar[u] = ar[u] + tr;  ai[u] = ai[u] + ti;
    }
  }
}

template<int SIGN>
__device__ __forceinline__ void fft32(float* ar, float* ai) {
  fft_stage<SIGN,1>(ar, ai);
  fft_stage<SIGN,2>(ar, ai);
  fft_stage<SIGN,3>(ar, ai);
  fft_stage<SIGN,4>(ar, ai);
  fft_stage<SIGN,5>(ar, ai);
}

// reflect-pad index mapping for v in [-32, 543], N=512 (mode='reflect', no edge dup)
__device__ __forceinline__ int refl(int v) {
  v = (v < 0) ? -v : v;
  return (v >= 512) ? (1022 - v) : v;
}

#define LSTR 33          // padded LDS row stride (floats)
#define CH_OFF (32*33)   // per-channel LDS offset = 1056

__global__ void wiener_patch(const float* __restrict__ I,
                             const float* __restrict__ S,
                             float* __restrict__ out)
{
  __shared__ float sre[3 * 32 * LSTR];
  __shared__ float sim[3 * 32 * LSTR];
  __shared__ float w1[32];
  __shared__ float red[6];

  int blk = blockIdx.x;
  int px  = blk % 67 + 1;  blk /= 67;
  int py  = blk % 67 + 1;
  int b   = blk / 67;
  const int t = threadIdx.x;

  if (t < 32) { float tt = (float)t - 15.5f; w1[t] = __expf(tt * tt * INV_WIN_DEN); }
  if (t < 6)  red[t] = 0.0f;
  __syncthreads();

  // ---- load 3x32x32 I patch into LDS (raw), accumulate per-channel sums ----
  float sI0=0.f, sI1=0.f, sI2=0.f, sS0=0.f, sS1=0.f, sS2=0.f;
  const int gy0 = py * 8 - 32, gx0 = px * 8 - 32;
  const int x  = t & 31;
  const int y0 = t >> 5;
  const int rx = refl(gx0 + x);
  const size_t bbase = (size_t)b * 3 * 262144;
  #pragma unroll
  for (int i = 0; i < 8; ++i) {
    int y  = y0 + 4 * i;
    int ry = refl(gy0 + y);
    size_t g = bbase + (size_t)ry * 512 + rx;
    float v0 = I[g];            float u0 = S[g];
    float v1 = I[g + 262144];   float u1 = S[g + 262144];
    float v2 = I[g + 524288];   float u2 = S[g + 524288];
    sI0 += v0; sI1 += v1; sI2 += v2;
    sS0 += u0; sS1 += u1; sS2 += u2;
    int l = y * LSTR + x;
    sre[l] = v0; sre[l + CH_OFF] = v1; sre[l + 2*CH_OFF] = v2;
  }
  // wave reduce (64 lanes), then one LDS atomic per wave
  #pragma unroll
  for (int off = 32; off > 0; off >>= 1) {
    sI0 += __shfl_down(sI0, off); sI1 += __shfl_down(sI1, off); sI2 += __shfl_down(sI2, off);
    sS0 += __shfl_down(sS0, off); sS1 += __shfl_down(sS1, off); sS2 += __shfl_down(sS2, off);
  }
  if ((t & 63) == 0) {
    atomicAdd(&red[0], sI0); atomicAdd(&red[1], sI1); atomicAdd(&red[2], sI2);
    atomicAdd(&red[3], sS0); atomicAdd(&red[4], sS1); atomicAdd(&red[5], sS2);
  }
  __syncthreads();

  const float meanI0 = red[0] * (1.f/1024.f);
  const float meanI1 = red[1] * (1.f/1024.f);
  const float meanI2 = red[2] * (1.f/1024.f);
  float s2 = 0.f;
  #pragma unroll
  for (int k = 0; k < 32; ++k) s2 += w1[k] * w1[k];   // uniform broadcast reads
  float mw = s2 * (1.f/32.f);
  const float mw2 = mw * mw;                          // mean(win^2)
  float sp0 = red[3] * (1.f/1024.f), sp1 = red[4] * (1.f/1024.f), sp2 = red[5] * (1.f/1024.f);
  const float Pvv0 = mw2 * 1024.f * sp0 * sp0;
  const float Pvv1 = mw2 * 1024.f * sp1 * sp1;
  const float Pvv2 = mw2 * 1024.f * sp2 * sp2;

  // ---- forward row FFTs (window + mean-subtract fused into load) ----
  if (t < 96) {
    float ar[32], ai[32];
    int c = t >> 5, yy = t & 31;
    const float wy = w1[yy];
    const float mc = (c == 0) ? meanI0 : ((c == 1) ? meanI1 : meanI2);
    const int rb = c * CH_OFF + yy * LSTR;
    #pragma unroll
    for (int i = 0; i < 32; ++i) {
      const int xs = REV5[i];
      ar[i] = (sre[rb + xs] - mc) * (wy * w1[xs]);
      ai[i] = 0.f;
    }
    fft32<-1>(ar, ai);
    #pragma unroll
    for (int i = 0; i < 32; ++i) { sre[rb + i] = ar[i]; sim[rb + i] = ai[i]; }
  }
  __syncthreads();

  // ---- forward column FFTs ----
  if (t < 96) {
    float ar[32], ai[32];
    int c = t >> 5, xx = t & 31;
    const int cb = c * CH_OFF + xx;
    #pragma unroll
    for (int i = 0; i < 32; ++i) {
      const int ys = REV5[i];
      ar[i] = sre[cb + LSTR * ys]; ai[i] = sim[cb + LSTR * ys];
    }
    fft32<-1>(ar, ai);
    #pragma unroll
    for (int i = 0; i < 32; ++i) { sre[cb + LSTR * i] = ar[i]; sim[cb + LSTR * i] = ai[i]; }
  }
  __syncthreads();

  // ---- channel DFT (len 3) + Wiener gain + inverse channel DFT ----
  {
    const int xx = t & 31, yb = t >> 5;
    #pragma unroll
    for (int i = 0; i < 8; ++i) {
      const int yy = yb + 4 * i;
      const int i0 = yy * LSTR + xx, i1 = i0 + CH_OFF, i2 = i0 + 2*CH_OFF;
      float a0r = sre[i0], a0i = sim[i0];
      float a1r = sre[i1], a1i = sim[i1];
      float a2r = sre[i2], a2i = sim[i2];
      float spr = a1r + a2r, spi = a1i + a2i;
      float smr = a1r - a2r, smi = a1i - a2i;
      float F0r = a0r + spr,        F0i = a0i + spi;
      float t1r = a0r - 0.5f*spr,   t1i = a0i - 0.5f*spi;
      float F1r = t1r + S3*smi,     F1i = t1i - S3*smr;
      float F2r = t1r - S3*smi,     F2i = t1i + S3*smr;
      float P0 = F0r*F0r + F0i*F0i + EPSF;
      float P1 = F1r*F1r + F1i*F1i + EPSF;
      float P2 = F2r*F2r + F2i*F2i + EPSF;
      float H0 = fmaxf(P0 - Pvv0, 0.f) / P0;
      float H1 = fmaxf(P1 - Pvv1, 0.f) / P1;
      float H2 = fmaxf(P2 - Pvv2, 0.f) / P2;
      F0r *= H0; F0i *= H0; F1r *= H1; F1i *= H1; F2r *= H2; F2i *= H2;
      float qpr = F1r + F2r, qpi = F1i + F2i;
      float qmr = F1r - F2r, qmi = F1i - F2i;
      float g0r = F0r + qpr,        g0i = F0i + qpi;
      float u1r = F0r - 0.5f*qpr,   u1i = F0i - 0.5f*qpi;
      float g1r = u1r - S3*qmi,     g1i = u1i + S3*qmr;
      float g2r = u1r + S3*qmi,     g2i = u1i - S3*qmr;
      sre[i0] = g0r; sim[i0] = g0i;
      sre[i1] = g1r; sim[i1] = g1i;
      sre[i2] = g2r; sim[i2] = g2i;
    }
  }
  __syncthreads();

  // ---- inverse column FFTs ----
  if (t < 96) {
    float ar[32], ai[32];
    int c = t >> 5, xx = t & 31;
    const int cb = c * CH_OFF + xx;
    #pragma unroll
    for (int i = 0; i < 32; ++i) {
      const int ys = REV5[i];
      ar[i] = sre[cb + LSTR * ys]; ai[i] = sim[cb + LSTR * ys];
    }
    fft32<+1>(ar, ai);
    #pragma unroll
    for (int i = 0; i < 32; ++i) { sre[cb + LSTR * i] = ar[i]; sim[cb + LSTR * i] = ai[i]; }
  }
  __syncthreads();

  // ---- inverse row FFTs + epilogue (re-window) + overlap-add via atomics ----
  if (t < 96) {
    float ar[32], ai[32];
    int c = t >> 5, yy = t & 31;
    const int rb = c * CH_OFF + yy * LSTR;
    #pragma unroll
    for (int i = 0; i < 32; ++i) {
      const int xs = REV5[i];
      ar[i] = sre[rb + xs]; ai[i] = sim[rb + xs];
    }
    fft32<+1>(ar, ai);
    const int oy = py * 8 + yy - 32;
    if (oy >= 0 && oy < 512) {
      const float wy = w1[yy];
      const float mc = (c == 0) ? meanI0 : ((c == 1) ? meanI1 : meanI2);
      float* dst = out + (((size_t)b * 3 + c) * 512 + oy) * 512;
      const int ox0 = px * 8 - 32;
      #pragma unroll
      for (int i = 0; i < 32; ++i) {
        const int ox = ox0 + i;
        if (ox >= 0 && ox < 512) {
          const float wv  = wy * w1[i];                 // win == win_interp (0.3 == 0.3)
          const float val = (ar[i] * (1.f/3072.f) + mc * wv) * wv;
          atomicAdd(dst + ox, val);
        }
      }
    }
  }
}

// IR = (acc + eps) / (mask + eps); mask(y,x) = mrow(y%8) * mrow(x%8),
// mrow(r) = sum_{k=0..3} w1[r+8k]^2   (win*win_interp == win^2, separable)
__global__ void wiener_norm(float* __restrict__ out)
{
  const int i = blockIdx.x * 256 + threadIdx.x;   // total 3,145,728 = 12288*256
  const int xx = i & 511;
  const int yy = (i >> 9) & 511;
  float my = 0.f, mx = 0.f;
  #pragma unroll
  for (int k = 0; k < 4; ++k) {
    float ty = (float)((yy & 7) + 8 * k) - 15.5f;
    float wy = __expf(ty * ty * INV_WIN_DEN);
    my += wy * wy;
    float tx = (float)((xx & 7) + 8 * k) - 15.5f;
    float wx = __expf(tx * tx * INV_WIN_DEN);
    mx += wx * wx;
  }
  out[i] = (out[i] + EPSF) / (my * mx + EPSF);
}

extern "C" void kernel_launch(void* const* d_in, const int* in_sizes, int n_in,
                              void* d_out, int out_size, void* d_ws, size_t ws_size,
                              hipStream_t stream)
{
  const float* I = (const float*)d_in[0];
  const float* S = (const float*)d_in[1];
  float* out = (float*)d_out;

  hipMemsetAsync(out, 0, (size_t)out_size * sizeof(float), stream);

  // only patches that intersect the cropped output: py,px in [1,67]
  const int nblocks = 4 * 67 * 67;
  wiener_patch<<<dim3(nblocks), dim3(128), 0, stream>>>(I, S, out);

  wiener_norm<<<dim3(out_size / 256), dim3(256), 0, stream>>>(out);
}

// Round 2
// 312.867 us; speedup vs baseline: 8.0255x; 8.0255x over previous
//
#include <hip/hip_runtime.h>

// ---------------------------------------------------------------------------
// Wiener 3D patch filter, MI355X.
// Input:  I (4,3,512,512) f32, noise_std (4,3,512,512) f32
// Output: (4,3,512,512) f32
// One 128-thread block per (b, py, px) patch location (py,px in [1,67]).
// Overlap-add via 16 parity planes in d_ws (no atomics); fallback to
// global atomics if ws_size is too small.
// ---------------------------------------------------------------------------

constexpr float TWR[16] = {
  1.0f, 0.98078528040323044f, 0.92387953251128674f, 0.83146961230254524f,
  0.70710678118654752f, 0.55557023301960222f, 0.38268343236508977f, 0.19509032201612827f,
  0.0f, -0.19509032201612827f, -0.38268343236508977f, -0.55557023301960222f,
  -0.70710678118654752f, -0.83146961230254524f, -0.92387953251128674f, -0.98078528040323044f
};
// TWI[k] = -sin(2*pi*k/32)  (forward twiddle imag part)
constexpr float TWI[16] = {
  -0.0f, -0.19509032201612827f, -0.38268343236508977f, -0.55557023301960222f,
  -0.70710678118654752f, -0.83146961230254524f, -0.92387953251128674f, -0.98078528040323044f,
  -1.0f, -0.98078528040323044f, -0.92387953251128674f, -0.83146961230254524f,
  -0.70710678118654752f, -0.55557023301960222f, -0.38268343236508977f, -0.19509032201612827f
};
constexpr int REV5[32] = {0,16,8,24,4,20,12,28,2,18,10,26,6,22,14,30,
                          1,17,9,25,5,21,13,29,3,19,11,27,7,23,15,31};

constexpr float S3   = 0.86602540378443865f;  // sqrt(3)/2
constexpr float EPSF = 1e-15f;
constexpr float INV_WIN_DEN = -1.0f / 76.8f;  // -1/(0.3*16*16)

#define PLANE_FLOATS (4 * 3 * 512 * 512)           // 3,145,728 per parity plane
#define WS_NEEDED    ((size_t)16 * PLANE_FLOATS * 4) // 201,326,592 bytes

template<int SIGN, int S>
__device__ __forceinline__ void fft_stage(float* ar, float* ai) {
  constexpr int m  = 1 << S;
  constexpr int h  = m >> 1;
  constexpr int ts = 32 >> S;
  #pragma unroll
  for (int k = 0; k < 32; k += m) {
    #pragma unroll
    for (int j = 0; j < h; ++j) {
      const float wr = TWR[j * ts];
      const float wi = (SIGN < 0) ? TWI[j * ts] : -TWI[j * ts];
      const int u = k + j, v = u + h;
      float tr = wr * ar[v] - wi * ai[v];
      float ti = wr * ai[v] + wi * ar[v];
      ar[v] = ar[u] - tr;  ai[v] = ai[u] - ti;
      ar[u] = ar[u] + tr;  ai[u] = ai[u] + ti;
    }
  }
}

template<int SIGN>
__device__ __forceinline__ void fft32(float* ar, float* ai) {
  fft_stage<SIGN,1>(ar, ai);
  fft_stage<SIGN,2>(ar, ai);
  fft_stage<SIGN,3>(ar, ai);
  fft_stage<SIGN,4>(ar, ai);
  fft_stage<SIGN,5>(ar, ai);
}

// reflect-pad index mapping for v in [-32, 543], N=512 (mode='reflect')
__device__ __forceinline__ int refl(int v) {
  v = (v < 0) ? -v : v;
  return (v >= 512) ? (1022 - v) : v;
}

#define LSTR 33          // padded LDS row stride (floats)
#define CH_OFF (32*33)   // per-channel LDS offset = 1056

// MODE 0: atomicAdd into out (fallback).  MODE 1: plain store into parity plane.
template<int MODE>
__global__ __launch_bounds__(128)
void wiener_patch(const float* __restrict__ I,
                  const float* __restrict__ S,
                  float* __restrict__ dst)   // MODE0: out, MODE1: ws planes
{
  __shared__ float sre[3 * 32 * LSTR];
  __shared__ float sim[3 * 32 * LSTR];
  __shared__ float w1[32];
  __shared__ float red[6];

  int blk = blockIdx.x;
  int px  = blk % 67 + 1;  blk /= 67;
  int py  = blk % 67 + 1;
  int b   = blk / 67;
  const int t = threadIdx.x;

  if (t < 32) { float tt = (float)t - 15.5f; w1[t] = __expf(tt * tt * INV_WIN_DEN); }
  if (t < 6)  red[t] = 0.0f;
  __syncthreads();

  // ---- load 3x32x32 I patch into LDS (raw), accumulate per-channel sums ----
  float sI0=0.f, sI1=0.f, sI2=0.f, sS0=0.f, sS1=0.f, sS2=0.f;
  const int gy0 = py * 8 - 32, gx0 = px * 8 - 32;
  const int x  = t & 31;
  const int y0 = t >> 5;
  const int rx = refl(gx0 + x);
  const size_t bbase = (size_t)b * 3 * 262144;
  #pragma unroll
  for (int i = 0; i < 8; ++i) {
    int y  = y0 + 4 * i;
    int ry = refl(gy0 + y);
    size_t g = bbase + (size_t)ry * 512 + rx;
    float v0 = I[g];            float u0 = S[g];
    float v1 = I[g + 262144];   float u1 = S[g + 262144];
    float v2 = I[g + 524288];   float u2 = S[g + 524288];
    sI0 += v0; sI1 += v1; sI2 += v2;
    sS0 += u0; sS1 += u1; sS2 += u2;
    int l = y * LSTR + x;
    sre[l] = v0; sre[l + CH_OFF] = v1; sre[l + 2*CH_OFF] = v2;
  }
  // wave reduce (64 lanes), then one LDS atomic per wave
  #pragma unroll
  for (int off = 32; off > 0; off >>= 1) {
    sI0 += __shfl_down(sI0, off); sI1 += __shfl_down(sI1, off); sI2 += __shfl_down(sI2, off);
    sS0 += __shfl_down(sS0, off); sS1 += __shfl_down(sS1, off); sS2 += __shfl_down(sS2, off);
  }
  if ((t & 63) == 0) {
    atomicAdd(&red[0], sI0); atomicAdd(&red[1], sI1); atomicAdd(&red[2], sI2);
    atomicAdd(&red[3], sS0); atomicAdd(&red[4], sS1); atomicAdd(&red[5], sS2);
  }
  __syncthreads();

  const float meanI0 = red[0] * (1.f/1024.f);
  const float meanI1 = red[1] * (1.f/1024.f);
  const float meanI2 = red[2] * (1.f/1024.f);
  float s2 = 0.f;
  #pragma unroll
  for (int k = 0; k < 32; ++k) s2 += w1[k] * w1[k];   // uniform broadcast reads
  float mw = s2 * (1.f/32.f);
  const float mw2 = mw * mw;                          // mean(win^2)
  float sp0 = red[3] * (1.f/1024.f), sp1 = red[4] * (1.f/1024.f), sp2 = red[5] * (1.f/1024.f);
  const float Pvv0 = mw2 * 1024.f * sp0 * sp0;
  const float Pvv1 = mw2 * 1024.f * sp1 * sp1;
  const float Pvv2 = mw2 * 1024.f * sp2 * sp2;

  // ---- forward row FFTs (window + mean-subtract fused into load) ----
  if (t < 96) {
    float ar[32], ai[32];
    int c = t >> 5, yy = t & 31;
    const float wy = w1[yy];
    const float mc = (c == 0) ? meanI0 : ((c == 1) ? meanI1 : meanI2);
    const int rb = c * CH_OFF + yy * LSTR;
    #pragma unroll
    for (int i = 0; i < 32; ++i) {
      const int xs = REV5[i];
      ar[i] = (sre[rb + xs] - mc) * (wy * w1[xs]);
      ai[i] = 0.f;
    }
    fft32<-1>(ar, ai);
    #pragma unroll
    for (int i = 0; i < 32; ++i) { sre[rb + i] = ar[i]; sim[rb + i] = ai[i]; }
  }
  __syncthreads();

  // ---- forward column FFTs ----
  if (t < 96) {
    float ar[32], ai[32];
    int c = t >> 5, xx = t & 31;
    const int cb = c * CH_OFF + xx;
    #pragma unroll
    for (int i = 0; i < 32; ++i) {
      const int ys = REV5[i];
      ar[i] = sre[cb + LSTR * ys]; ai[i] = sim[cb + LSTR * ys];
    }
    fft32<-1>(ar, ai);
    #pragma unroll
    for (int i = 0; i < 32; ++i) { sre[cb + LSTR * i] = ar[i]; sim[cb + LSTR * i] = ai[i]; }
  }
  __syncthreads();

  // ---- channel DFT (len 3) + Wiener gain + inverse channel DFT ----
  {
    const int xx = t & 31, yb = t >> 5;
    #pragma unroll
    for (int i = 0; i < 8; ++i) {
      const int yy = yb + 4 * i;
      const int i0 = yy * LSTR + xx, i1 = i0 + CH_OFF, i2 = i0 + 2*CH_OFF;
      float a0r = sre[i0], a0i = sim[i0];
      float a1r = sre[i1], a1i = sim[i1];
      float a2r = sre[i2], a2i = sim[i2];
      float spr = a1r + a2r, spi = a1i + a2i;
      float smr = a1r - a2r, smi = a1i - a2i;
      float F0r = a0r + spr,        F0i = a0i + spi;
      float t1r = a0r - 0.5f*spr,   t1i = a0i - 0.5f*spi;
      float F1r = t1r + S3*smi,     F1i = t1i - S3*smr;
      float F2r = t1r - S3*smi,     F2i = t1i + S3*smr;
      float P0 = F0r*F0r + F0i*F0i + EPSF;
      float P1 = F1r*F1r + F1i*F1i + EPSF;
      float P2 = F2r*F2r + F2i*F2i + EPSF;
      float H0 = fmaxf(P0 - Pvv0, 0.f) / P0;
      float H1 = fmaxf(P1 - Pvv1, 0.f) / P1;
      float H2 = fmaxf(P2 - Pvv2, 0.f) / P2;
      F0r *= H0; F0i *= H0; F1r *= H1; F1i *= H1; F2r *= H2; F2i *= H2;
      float qpr = F1r + F2r, qpi = F1i + F2i;
      float qmr = F1r - F2r, qmi = F1i - F2i;
      float g0r = F0r + qpr,        g0i = F0i + qpi;
      float u1r = F0r - 0.5f*qpr,   u1i = F0i - 0.5f*qpi;
      float g1r = u1r - S3*qmi,     g1i = u1i + S3*qmr;
      float g2r = u1r + S3*qmi,     g2i = u1i - S3*qmr;
      sre[i0] = g0r; sim[i0] = g0i;
      sre[i1] = g1r; sim[i1] = g1i;
      sre[i2] = g2r; sim[i2] = g2i;
    }
  }
  __syncthreads();

  // ---- inverse column FFTs ----
  if (t < 96) {
    float ar[32], ai[32];
    int c = t >> 5, xx = t & 31;
    const int cb = c * CH_OFF + xx;
    #pragma unroll
    for (int i = 0; i < 32; ++i) {
      const int ys = REV5[i];
      ar[i] = sre[cb + LSTR * ys]; ai[i] = sim[cb + LSTR * ys];
    }
    fft32<+1>(ar, ai);
    #pragma unroll
    for (int i = 0; i < 32; ++i) { sre[cb + LSTR * i] = ar[i]; sim[cb + LSTR * i] = ai[i]; }
  }
  __syncthreads();

  // ---- inverse row FFTs, result (real part) back to LDS ----
  if (t < 96) {
    float ar[32], ai[32];
    int c = t >> 5, yy = t & 31;
    const int rb = c * CH_OFF + yy * LSTR;
    #pragma unroll
    for (int i = 0; i < 32; ++i) {
      const int xs = REV5[i];
      ar[i] = sre[rb + xs]; ai[i] = sim[rb + xs];
    }
    fft32<+1>(ar, ai);
    #pragma unroll
    for (int i = 0; i < 32; ++i) sre[rb + i] = ar[i];
  }
  __syncthreads();

  // ---- coalesced epilogue: window + mean add, store (plane or atomic) ----
  const int oy0 = py * 8 - 32, ox0 = px * 8 - 32;
  float* plane = (MODE == 1)
      ? dst + ((size_t)(((py & 3) << 2) | (px & 3)) * PLANE_FLOATS + (size_t)b * 3 * 262144)
      : dst + (size_t)b * 3 * 262144;
  for (int j = t; j < 3072; j += 128) {
    const int xx = j & 31, yy = (j >> 5) & 31, c = j >> 10;
    const int oy = oy0 + yy, ox = ox0 + xx;
    if (oy >= 0 && oy < 512 && ox >= 0 && ox < 512) {
      const float wv = w1[yy] * w1[xx];               // win == win_interp
      const float mc = (c == 0) ? meanI0 : ((c == 1) ? meanI1 : meanI2);
      const float val = (sre[c * CH_OFF + yy * LSTR + xx] * (1.f/3072.f) + mc * wv) * wv;
      float* p = plane + ((size_t)c * 512 + oy) * 512 + ox;
      if (MODE == 1) *p = val;
      else           atomicAdd(p, val);
    }
  }
}

// mask(y,x) = mrow(y%8) * mrow(x%8), mrow(r) = sum_k w1[r+8k]^2
__device__ __forceinline__ float mask_row(int r) {
  float m = 0.f;
  #pragma unroll
  for (int k = 0; k < 4; ++k) {
    float tt = (float)(r + 8 * k) - 15.5f;
    float w = __expf(tt * tt * INV_WIN_DEN);
    m += w * w;
  }
  return m;
}

// MODE1 phase 2: out = (sum of 16 planes + eps) / (mask + eps)
__global__ void wiener_combine(const float* __restrict__ ws, float* __restrict__ out)
{
  const int i = blockIdx.x * 256 + threadIdx.x;   // out_size = 3,145,728
  const int xx = i & 511;
  const int yy = (i >> 9) & 511;
  float s = 0.f;
  #pragma unroll
  for (int p = 0; p < 16; ++p) s += ws[(size_t)p * PLANE_FLOATS + i];
  out[i] = (s + EPSF) / (mask_row(yy & 7) * mask_row(xx & 7) + EPSF);
}

// MODE0 phase 2: in-place normalize after atomic accumulation
__global__ void wiener_norm(float* __restrict__ out)
{
  const int i = blockIdx.x * 256 + threadIdx.x;
  const int xx = i & 511;
  const int yy = (i >> 9) & 511;
  out[i] = (out[i] + EPSF) / (mask_row(yy & 7) * mask_row(xx & 7) + EPSF);
}

extern "C" void kernel_launch(void* const* d_in, const int* in_sizes, int n_in,
                              void* d_out, int out_size, void* d_ws, size_t ws_size,
                              hipStream_t stream)
{
  const float* I = (const float*)d_in[0];
  const float* S = (const float*)d_in[1];
  float* out = (float*)d_out;
  const int nblocks = 4 * 67 * 67;       // patches intersecting the crop

  if (ws_size >= WS_NEEDED && d_ws != nullptr) {
    float* ws = (float*)d_ws;
    // every in-crop plane pixel is written exactly once -> no zeroing needed
    wiener_patch<1><<<dim3(nblocks), dim3(128), 0, stream>>>(I, S, ws);
    wiener_combine<<<dim3(out_size / 256), dim3(256), 0, stream>>>(ws, out);
  } else {
    hipMemsetAsync(out, 0, (size_t)out_size * sizeof(float), stream);
    wiener_patch<0><<<dim3(nblocks), dim3(128), 0, stream>>>(I, S, out);
    wiener_norm<<<dim3(out_size / 256), dim3(256), 0, stream>>>(out);
  }
}

// Round 3
// 261.964 us; speedup vs baseline: 9.5849x; 1.1943x over previous
//
#include <hip/hip_runtime.h>

// ---------------------------------------------------------------------------
// Wiener 3D patch filter, MI355X.
// Input:  I (4,3,512,512) f32, noise_std (4,3,512,512) f32
// Output: (4,3,512,512) f32
// 2 patches per 256-thread block; FFT passes use 192 threads (3 full waves).
// Overlap-add via 16 parity planes in d_ws (no atomics); fallback to
// global atomics if ws_size is too small.
// ---------------------------------------------------------------------------

constexpr float TWR[16] = {
  1.0f, 0.98078528040323044f, 0.92387953251128674f, 0.83146961230254524f,
  0.70710678118654752f, 0.55557023301960222f, 0.38268343236508977f, 0.19509032201612827f,
  0.0f, -0.19509032201612827f, -0.38268343236508977f, -0.55557023301960222f,
  -0.70710678118654752f, -0.83146961230254524f, -0.92387953251128674f, -0.98078528040323044f
};
// TWI[k] = -sin(2*pi*k/32)  (forward twiddle imag part)
constexpr float TWI[16] = {
  -0.0f, -0.19509032201612827f, -0.38268343236508977f, -0.55557023301960222f,
  -0.70710678118654752f, -0.83146961230254524f, -0.92387953251128674f, -0.98078528040323044f,
  -1.0f, -0.98078528040323044f, -0.92387953251128674f, -0.83146961230254524f,
  -0.70710678118654752f, -0.55557023301960222f, -0.38268343236508977f, -0.19509032201612827f
};
constexpr int REV5[32] = {0,16,8,24,4,20,12,28,2,18,10,26,6,22,14,30,
                          1,17,9,25,5,21,13,29,3,19,11,27,7,23,15,31};

constexpr float S3   = 0.86602540378443865f;  // sqrt(3)/2
constexpr float EPSF = 1e-15f;
constexpr float INV_WIN_DEN = -1.0f / 76.8f;  // -1/(0.3*16*16)

#define PLANE_FLOATS (4 * 3 * 512 * 512)             // 3,145,728 per parity plane
#define WS_NEEDED    ((size_t)16 * PLANE_FLOATS * 4) // 201,326,592 bytes

// ---- butterfly with compile-time twiddle specialization ----
template<int SIGN, int K>
__device__ __forceinline__ void bfly(float& ur, float& ui, float& vr, float& vi) {
  if constexpr (K == 0) {
    float tr = vr, ti = vi;
    vr = ur - tr; vi = ui - ti; ur += tr; ui += ti;
  } else if constexpr (K == 8) {
    // fwd: w = -i -> t = (vi, -vr);  inv: w = +i -> t = (-vi, vr)
    float tr = (SIGN < 0) ?  vi : -vi;
    float ti = (SIGN < 0) ? -vr :  vr;
    vr = ur - tr; vi = ui - ti; ur += tr; ui += ti;
  } else {
    constexpr float wr = TWR[K];
    constexpr float wi = (SIGN < 0) ? TWI[K] : -TWI[K];
    float tr = wr * vr - wi * vi;
    float ti = wr * vi + wi * vr;
    vr = ur - tr; vi = ui - ti; ur += tr; ui += ti;
  }
}

template<int SIGN, int S, int J>
__device__ __forceinline__ void stage_j(float* ar, float* ai) {
  constexpr int m = 1 << S, h = m >> 1, ts = 32 >> S;
  if constexpr (J < h) {
    #pragma unroll
    for (int k = 0; k < 32; k += m)
      bfly<SIGN, J * ts>(ar[k + J], ai[k + J], ar[k + J + h], ai[k + J + h]);
    stage_j<SIGN, S, J + 1>(ar, ai);
  }
}

template<int SIGN>
__device__ __forceinline__ void fft32(float* ar, float* ai) {
  stage_j<SIGN, 1, 0>(ar, ai);
  stage_j<SIGN, 2, 0>(ar, ai);
  stage_j<SIGN, 3, 0>(ar, ai);
  stage_j<SIGN, 4, 0>(ar, ai);
  stage_j<SIGN, 5, 0>(ar, ai);
}

// reflect-pad index mapping for v in [-32, 543], N=512 (mode='reflect')
__device__ __forceinline__ int refl(int v) {
  v = (v < 0) ? -v : v;
  return (v >= 512) ? (1022 - v) : v;
}

#define LSTR 33            // padded LDS row stride (floats)
#define CH_OFF (32*33)     // per-channel LDS plane = 1056 floats
#define PSZ (3*CH_OFF)     // per-patch LDS = 3168 floats

// MODE 0: atomicAdd into out (fallback).  MODE 1: plain store into parity plane.
template<int MODE>
__global__ __launch_bounds__(256)
void wiener_patch(const float* __restrict__ I,
                  const float* __restrict__ S,
                  float* __restrict__ dst)   // MODE0: out, MODE1: ws planes
{
  __shared__ float sre[2 * PSZ];
  __shared__ float sim[2 * PSZ];
  __shared__ float w1[32];
  __shared__ float red[12];
  __shared__ float sw2s;

  const int t  = threadIdx.x;
  const int q  = t >> 7;          // patch slot 0/1
  const int tl = t & 127;

  const int P  = blockIdx.x * 2 + q;
  int pp = P;
  const int px = pp % 67 + 1;  pp /= 67;
  const int py = pp % 67 + 1;
  const int b  = pp / 67;

  if (t < 32) { float tt = (float)t - 15.5f; w1[t] = __expf(tt * tt * INV_WIN_DEN); }
  if (t < 12) red[t] = 0.0f;
  __syncthreads();

  // ---- load 3x32x32 I patch into LDS (raw), accumulate per-channel sums ----
  float sI0=0.f, sI1=0.f, sI2=0.f, sS0=0.f, sS1=0.f, sS2=0.f;
  {
    const int gy0 = py * 8 - 32, gx0 = px * 8 - 32;
    const int x  = tl & 31;
    const int y0 = tl >> 5;
    const int rx = refl(gx0 + x);
    const size_t bbase = (size_t)b * 3 * 262144;
    #pragma unroll
    for (int i = 0; i < 8; ++i) {
      int y  = y0 + 4 * i;
      int ry = refl(gy0 + y);
      size_t g = bbase + (size_t)ry * 512 + rx;
      float v0 = I[g];            float u0 = S[g];
      float v1 = I[g + 262144];   float u1 = S[g + 262144];
      float v2 = I[g + 524288];   float u2 = S[g + 524288];
      sI0 += v0; sI1 += v1; sI2 += v2;
      sS0 += u0; sS1 += u1; sS2 += u2;
      int l = q * PSZ + y * LSTR + x;
      sre[l] = v0; sre[l + CH_OFF] = v1; sre[l + 2*CH_OFF] = v2;
    }
  }
  if (t == 0) {                 // shared (mean win)^2 helper: (sum(w^2)/32)^2
    float s2 = 0.f;
    #pragma unroll
    for (int k = 0; k < 32; ++k) s2 += w1[k] * w1[k];
    float mw = s2 * (1.f/32.f);
    sw2s = mw * mw;
  }
  // wave reduce (64 lanes all same patch), then one LDS atomic per wave
  #pragma unroll
  for (int off = 32; off > 0; off >>= 1) {
    sI0 += __shfl_down(sI0, off); sI1 += __shfl_down(sI1, off); sI2 += __shfl_down(sI2, off);
    sS0 += __shfl_down(sS0, off); sS1 += __shfl_down(sS1, off); sS2 += __shfl_down(sS2, off);
  }
  if ((t & 63) == 0) {
    atomicAdd(&red[q*6+0], sI0); atomicAdd(&red[q*6+1], sI1); atomicAdd(&red[q*6+2], sI2);
    atomicAdd(&red[q*6+3], sS0); atomicAdd(&red[q*6+4], sS1); atomicAdd(&red[q*6+5], sS2);
  }
  __syncthreads();

  // ---- forward row FFTs (window + mean-subtract fused into load) ----
  if (t < 192) {
    float ar[32], ai[32];
    const int cc = t >> 5, yy = t & 31;          // cc in [0,6): patch=cc/3, ch=cc%3
    const float wy = w1[yy];
    const float mc = red[cc + ((cc >= 3) ? 3 : 0)] * (1.f/1024.f);
    const int rb = cc * CH_OFF + yy * LSTR;
    #pragma unroll
    for (int i = 0; i < 32; ++i) {
      const int xs = REV5[i];
      ar[i] = (sre[rb + xs] - mc) * (wy * w1[xs]);
      ai[i] = 0.f;
    }
    fft32<-1>(ar, ai);
    #pragma unroll
    for (int i = 0; i < 32; ++i) { sre[rb + i] = ar[i]; sim[rb + i] = ai[i]; }
  }
  __syncthreads();

  // ---- forward column FFTs ----
  if (t < 192) {
    float ar[32], ai[32];
    const int cc = t >> 5, xx = t & 31;
    const int cb = cc * CH_OFF + xx;
    #pragma unroll
    for (int i = 0; i < 32; ++i) {
      const int ys = REV5[i];
      ar[i] = sre[cb + LSTR * ys]; ai[i] = sim[cb + LSTR * ys];
    }
    fft32<-1>(ar, ai);
    #pragma unroll
    for (int i = 0; i < 32; ++i) { sre[cb + LSTR * i] = ar[i]; sim[cb + LSTR * i] = ai[i]; }
  }
  __syncthreads();

  // ---- channel DFT (len 3) + Wiener gain + inverse channel DFT ----
  {
    const float inv1024 = 1.f/1024.f;
    const float mw2 = sw2s;
    const float sp0 = red[q*6+3] * inv1024, sp1 = red[q*6+4] * inv1024, sp2 = red[q*6+5] * inv1024;
    const float Pvv0 = mw2 * 1024.f * sp0 * sp0;
    const float Pvv1 = mw2 * 1024.f * sp1 * sp1;
    const float Pvv2 = mw2 * 1024.f * sp2 * sp2;
    const int xx = tl & 31, yb = tl >> 5;
    #pragma unroll
    for (int i = 0; i < 8; ++i) {
      const int yy = yb + 4 * i;
      const int i0 = q * PSZ + yy * LSTR + xx, i1 = i0 + CH_OFF, i2 = i0 + 2*CH_OFF;
      float a0r = sre[i0], a0i = sim[i0];
      float a1r = sre[i1], a1i = sim[i1];
      float a2r = sre[i2], a2i = sim[i2];
      float spr = a1r + a2r, spi = a1i + a2i;
      float smr = a1r - a2r, smi = a1i - a2i;
      float F0r = a0r + spr,        F0i = a0i + spi;
      float t1r = a0r - 0.5f*spr,   t1i = a0i - 0.5f*spi;
      float F1r = t1r + S3*smi,     F1i = t1i - S3*smr;
      float F2r = t1r - S3*smi,     F2i = t1i + S3*smr;
      float P0 = F0r*F0r + F0i*F0i + EPSF;
      float P1 = F1r*F1r + F1i*F1i + EPSF;
      float P2 = F2r*F2r + F2i*F2i + EPSF;
      float H0 = fmaxf(P0 - Pvv0, 0.f) / P0;
      float H1 = fmaxf(P1 - Pvv1, 0.f) / P1;
      float H2 = fmaxf(P2 - Pvv2, 0.f) / P2;
      F0r *= H0; F0i *= H0; F1r *= H1; F1i *= H1; F2r *= H2; F2i *= H2;
      float qpr = F1r + F2r, qpi = F1i + F2i;
      float qmr = F1r - F2r, qmi = F1i - F2i;
      float g0r = F0r + qpr,        g0i = F0i + qpi;
      float u1r = F0r - 0.5f*qpr,   u1i = F0i - 0.5f*qpi;
      float g1r = u1r - S3*qmi,     g1i = u1i + S3*qmr;
      float g2r = u1r + S3*qmi,     g2i = u1i - S3*qmr;
      sre[i0] = g0r; sim[i0] = g0i;
      sre[i1] = g1r; sim[i1] = g1i;
      sre[i2] = g2r; sim[i2] = g2i;
    }
  }
  __syncthreads();

  // ---- inverse column FFTs ----
  if (t < 192) {
    float ar[32], ai[32];
    const int cc = t >> 5, xx = t & 31;
    const int cb = cc * CH_OFF + xx;
    #pragma unroll
    for (int i = 0; i < 32; ++i) {
      const int ys = REV5[i];
      ar[i] = sre[cb + LSTR * ys]; ai[i] = sim[cb + LSTR * ys];
    }
    fft32<+1>(ar, ai);
    #pragma unroll
    for (int i = 0; i < 32; ++i) { sre[cb + LSTR * i] = ar[i]; sim[cb + LSTR * i] = ai[i]; }
  }
  __syncthreads();

  // ---- inverse row FFTs, real part back to LDS ----
  if (t < 192) {
    float ar[32], ai[32];
    const int cc = t >> 5, yy = t & 31;
    const int rb = cc * CH_OFF + yy * LSTR;
    #pragma unroll
    for (int i = 0; i < 32; ++i) {
      const int xs = REV5[i];
      ar[i] = sre[rb + xs]; ai[i] = sim[rb + xs];
    }
    fft32<+1>(ar, ai);
    #pragma unroll
    for (int i = 0; i < 32; ++i) sre[rb + i] = ar[i];
  }
  __syncthreads();

  // ---- coalesced epilogue: window + mean add, store (plane or atomic) ----
  {
    const int oy0 = py * 8 - 32, ox0 = px * 8 - 32;
    float* plane = (MODE == 1)
        ? dst + ((size_t)(((py & 3) << 2) | (px & 3)) * PLANE_FLOATS + (size_t)b * 3 * 262144)
        : dst + (size_t)b * 3 * 262144;
    const float m0 = red[q*6+0] * (1.f/1024.f);
    const float m1 = red[q*6+1] * (1.f/1024.f);
    const float m2 = red[q*6+2] * (1.f/1024.f);
    for (int j = tl; j < 3072; j += 128) {
      const int xx = j & 31, yy = (j >> 5) & 31, c = j >> 10;
      const int oy = oy0 + yy, ox = ox0 + xx;
      if (oy >= 0 && oy < 512 && ox >= 0 && ox < 512) {
        const float wv = w1[yy] * w1[xx];               // win == win_interp
        const float mc = (c == 0) ? m0 : ((c == 1) ? m1 : m2);
        const float val = (sre[q * PSZ + c * CH_OFF + yy * LSTR + xx] * (1.f/3072.f) + mc * wv) * wv;
        float* p = plane + ((size_t)c * 512 + oy) * 512 + ox;
        if (MODE == 1) *p = val;
        else           atomicAdd(p, val);
      }
    }
  }
}

// mask(y,x) = mrow(y%8) * mrow(x%8), mrow(r) = sum_k w1[r+8k]^2
__device__ __forceinline__ float mask_row(int r) {
  float m = 0.f;
  #pragma unroll
  for (int k = 0; k < 4; ++k) {
    float tt = (float)(r + 8 * k) - 15.5f;
    float w = __expf(tt * tt * INV_WIN_DEN);
    m += w * w;
  }
  return m;
}

// MODE1 phase 2: out = (sum of 16 planes + eps) / (mask + eps)
__global__ void wiener_combine(const float* __restrict__ ws, float* __restrict__ out)
{
  const int i = blockIdx.x * 256 + threadIdx.x;   // out_size = 3,145,728
  const int xx = i & 511;
  const int yy = (i >> 9) & 511;
  float s = 0.f;
  #pragma unroll
  for (int p = 0; p < 16; ++p) s += ws[(size_t)p * PLANE_FLOATS + i];
  out[i] = (s + EPSF) / (mask_row(yy & 7) * mask_row(xx & 7) + EPSF);
}

// MODE0 phase 2: in-place normalize after atomic accumulation
__global__ void wiener_norm(float* __restrict__ out)
{
  const int i = blockIdx.x * 256 + threadIdx.x;
  const int xx = i & 511;
  const int yy = (i >> 9) & 511;
  out[i] = (out[i] + EPSF) / (mask_row(yy & 7) * mask_row(xx & 7) + EPSF);
}

extern "C" void kernel_launch(void* const* d_in, const int* in_sizes, int n_in,
                              void* d_out, int out_size, void* d_ws, size_t ws_size,
                              hipStream_t stream)
{
  const float* I = (const float*)d_in[0];
  const float* S = (const float*)d_in[1];
  float* out = (float*)d_out;
  const int nblocks = (4 * 67 * 67) / 2;   // 2 patches per block, 17956 total

  if (ws_size >= WS_NEEDED && d_ws != nullptr) {
    float* ws = (float*)d_ws;
    // every in-crop plane pixel is written exactly once -> no zeroing needed
    wiener_patch<1><<<dim3(nblocks), dim3(256), 0, stream>>>(I, S, ws);
    wiener_combine<<<dim3(out_size / 256), dim3(256), 0, stream>>>(ws, out);
  } else {
    hipMemsetAsync(out, 0, (size_t)out_size * sizeof(float), stream);
    wiener_patch<0><<<dim3(nblocks), dim3(256), 0, stream>>>(I, S, out);
    wiener_norm<<<dim3(out_size / 256), dim3(256), 0, stream>>>(out);
  }
}